// Round 1
// baseline (1611.722 us; speedup 1.0000x reference)
//
#include <hip/hip_runtime.h>
#include <cstdint>
#include <cstddef>

// Problem constants
#define BB 4
#define SS 4096
#define HH 1024
#define PP 10
#define LL 4106          // P + S
#define LPAD 4128        // 129 * 32 (zero-padded KV length, Path A)
#define NTILES 129       // KV tiles of 32
#define LOG2E 1.44269504088896f

typedef __attribute__((ext_vector_type(8))) short short8v;   // 8 x bf16 MFMA frag (4 VGPRs)
typedef __attribute__((ext_vector_type(4))) float float4v;
typedef __attribute__((ext_vector_type(4))) unsigned int uint4v;

union frag_cast { uint4v u; short8v s; };

// bf16 round-to-nearest-even of one float -> low 16 bits
__device__ __forceinline__ unsigned bf16rn1(float x) {
  unsigned u = __float_as_uint(x);
  return (u + 0x7FFFu + ((u >> 16) & 1u)) >> 16;
}
__device__ __forceinline__ unsigned packrn(float a, float b) {
  return bf16rn1(a) | (bf16rn1(b) << 16);
}
// truncated-high part (so lo = x - hi is exact)
__device__ __forceinline__ float trunchi(float a) {
  return __uint_as_float(__float_as_uint(a) & 0xFFFF0000u);
}
__device__ __forceinline__ unsigned packtrunc(float a, float b) {
  return (__float_as_uint(a) >> 16) | (__float_as_uint(b) & 0xFFFF0000u);
}

// 8 fp32 -> bf16 hi frag (truncate) + bf16 lo frag (RN of exact residual)
__device__ __forceinline__ void mk_hilo(float4v f0, float4v f1, short8v& hv, short8v& lv) {
  frag_cast h, lo;
  float a0 = f0[0], a1 = f0[1], a2 = f0[2], a3 = f0[3];
  float a4 = f1[0], a5 = f1[1], a6 = f1[2], a7 = f1[3];
  h.u[0] = packtrunc(a0, a1); h.u[1] = packtrunc(a2, a3);
  h.u[2] = packtrunc(a4, a5); h.u[3] = packtrunc(a6, a7);
  lo.u[0] = packrn(a0 - trunchi(a0), a1 - trunchi(a1));
  lo.u[1] = packrn(a2 - trunchi(a2), a3 - trunchi(a3));
  lo.u[2] = packrn(a4 - trunchi(a4), a5 - trunchi(a5));
  lo.u[3] = packrn(a6 - trunchi(a6), a7 - trunchi(a7));
  hv = h.s; lv = lo.s;
}

// ---------------- Path A pre-kernels ----------------
// K_hi/K_lo: [4][LPAD][1024] bf16 planes, prefix-concatenated, zero-padded rows >= LL.
__global__ __launch_bounds__(256) void conv_k(const float* __restrict__ prefix_k,
                                              const float* __restrict__ key,
                                              unsigned short* __restrict__ k_hi,
                                              unsigned short* __restrict__ k_lo) {
  int id = blockIdx.x * 256 + threadIdx.x;   // 4*LPAD*128 total
  int chunk = id & 127;
  int row = id >> 7;                         // b*LPAD + n
  int b = row / LPAD;
  int n = row - b * LPAD;
  int col = chunk * 8;
  float4v f0 = {0.f, 0.f, 0.f, 0.f}, f1 = {0.f, 0.f, 0.f, 0.f};
  if (n < LL) {
    const float* src = (n < PP) ? (prefix_k + (size_t)n * HH + col)
                                : (key + ((size_t)b * SS + (n - PP)) * HH + col);
    f0 = *(const float4v*)src;
    f1 = *(const float4v*)(src + 4);
  }
  short8v hv, lv;
  mk_hilo(f0, f1, hv, lv);
  size_t off = (size_t)row * HH + col;
  *(short8v*)(k_hi + off) = hv;
  *(short8v*)(k_lo + off) = lv;
}

// V^T: [4][1024][LPAD] bf16, transposed + prefix-concatenated + zero-padded.
__global__ __launch_bounds__(256) void conv_v(const float* __restrict__ prefix_v,
                                              const float* __restrict__ value,
                                              unsigned short* __restrict__ v_t) {
  __shared__ float tile[32][68];   // padded stride, 32 n x 64 d
  int nt = blockIdx.x, dt = blockIdx.y, b = blockIdx.z;
  int t = threadIdx.x;
  #pragma unroll
  for (int p = 0; p < 2; ++p) {
    int nl = p * 16 + (t >> 4);
    int n = nt * 32 + nl;
    int d = dt * 64 + (t & 15) * 4;
    float4v f = {0.f, 0.f, 0.f, 0.f};
    if (n < LL) {
      const float* src = (n < PP) ? (prefix_v + (size_t)n * HH + d)
                                  : (value + ((size_t)b * SS + (n - PP)) * HH + d);
      f = *(const float4v*)src;
    }
    *(float4v*)&tile[nl][(t & 15) * 4] = f;
  }
  __syncthreads();
  int dl = t >> 2;           // 0..63
  int nch = (t & 3) * 8;     // 0,8,16,24
  uint4v outv;
  #pragma unroll
  for (int j = 0; j < 4; ++j)
    outv[j] = packrn(tile[nch + 2 * j][dl], tile[nch + 2 * j + 1][dl]);
  size_t off = ((size_t)b * HH + dt * 64 + dl) * LPAD + nt * 32 + nch;
  frag_cast fc; fc.u = outv;
  *(short8v*)(v_t + off) = fc.s;
}

// ---------------- fused flash attention ----------------
// 8 waves/WG; wave w owns D-slice [128w,128w+128). M=32 Q rows/WG, KV tile N=32.
// PATH 0: preconverted K_hi/K_lo/V^T in ws. PATH 1: on-the-fly fp32->bf16, masked tail.
template<int PATH>
__global__ __launch_bounds__(512, 2) void attn_fused(
    const float* __restrict__ q,
    const float* __restrict__ key,
    const float* __restrict__ value,
    const float* __restrict__ prefix_k,
    const float* __restrict__ prefix_v,
    const unsigned short* __restrict__ k_hi,
    const unsigned short* __restrict__ k_lo,
    const unsigned short* __restrict__ v_t,
    float* __restrict__ out)
{
  __shared__ __align__(16) float buf[8][32][34];        // per-wave partial S, stride 34 (bank-safe)
  __shared__ __align__(16) unsigned short Pl[32][40];   // P tile bf16, stride 40 (16B-aligned rows)
  __shared__ float m_l[32], l_l[32], sc_l[32];

  const int tid = threadIdx.x;
  const int w = tid >> 6;
  const int ln = tid & 63;
  const int g = ln >> 4;     // 16-lane group
  const int li = ln & 15;

  // XCD-aware mapping: batch b pinned to XCDs {2b,2b+1} so K/V stream is L2-resident.
  const int bid = blockIdx.x;
  const int xcd = bid & 7;
  const int b = xcd >> 1;
  const int qt = ((bid >> 3) << 1) | (xcd & 1);   // 0..127
  const int q0 = qt * 32;
  const int dbase = w * 128;

  // Q fragments (hi/lo), A-operand layout: row = li, k = g*8 + j
  short8v qhi[2][4], qlo[2][4];
  #pragma unroll
  for (int mt = 0; mt < 2; ++mt)
    #pragma unroll
    for (int kt = 0; kt < 4; ++kt) {
      const float* p = q + ((size_t)(b * SS + q0 + mt * 16 + li)) * HH + dbase + kt * 32 + g * 8;
      mk_hilo(*(const float4v*)p, *(const float4v*)(p + 4), qhi[mt][kt], qlo[mt][kt]);
    }

  float4v o[2][8];
  float4v z4 = {0.f, 0.f, 0.f, 0.f};
  #pragma unroll
  for (int mt = 0; mt < 2; ++mt)
    #pragma unroll
    for (int dt = 0; dt < 8; ++dt) o[mt][dt] = z4;

  if (tid < 32) { m_l[tid] = -1e30f; l_l[tid] = 0.f; }

  for (int it = 0; it < NTILES; ++it) {
    const int n0 = it * 32;

    // ---- phase 1: partial QK^T over this wave's D-slice (bf16x3) ----
    float4v sacc[2][2];
    sacc[0][0] = z4; sacc[0][1] = z4; sacc[1][0] = z4; sacc[1][1] = z4;
    #pragma unroll
    for (int kt = 0; kt < 4; ++kt) {
      short8v kh[2], kl2[2];
      #pragma unroll
      for (int nt = 0; nt < 2; ++nt) {
        const int n = n0 + nt * 16 + li;
        if constexpr (PATH == 0) {
          size_t off = ((size_t)(b * LPAD + n)) * HH + dbase + kt * 32 + g * 8;
          kh[nt]  = *(const short8v*)(k_hi + off);
          kl2[nt] = *(const short8v*)(k_lo + off);
        } else {
          const int nc = (n < LL) ? n : 0;   // clamp; masked in softmax
          const float* kp = (nc < PP) ? (prefix_k + (size_t)nc * HH)
                                      : (key + ((size_t)b * SS + (nc - PP)) * HH);
          kp += dbase + kt * 32 + g * 8;
          mk_hilo(*(const float4v*)kp, *(const float4v*)(kp + 4), kh[nt], kl2[nt]);
        }
      }
      #pragma unroll
      for (int mt = 0; mt < 2; ++mt)
        #pragma unroll
        for (int nt = 0; nt < 2; ++nt) {
          sacc[mt][nt] = __builtin_amdgcn_mfma_f32_16x16x32_bf16(qhi[mt][kt], kh[nt],  sacc[mt][nt], 0, 0, 0);
          sacc[mt][nt] = __builtin_amdgcn_mfma_f32_16x16x32_bf16(qhi[mt][kt], kl2[nt], sacc[mt][nt], 0, 0, 0);
          sacc[mt][nt] = __builtin_amdgcn_mfma_f32_16x16x32_bf16(qlo[mt][kt], kh[nt],  sacc[mt][nt], 0, 0, 0);
        }
    }
    // C/D layout: row = g*4 + reg, col = li  [HW-verified mapping]
    #pragma unroll
    for (int mt = 0; mt < 2; ++mt)
      #pragma unroll
      for (int nt = 0; nt < 2; ++nt)
        #pragma unroll
        for (int r = 0; r < 4; ++r)
          buf[w][mt * 16 + g * 4 + r][nt * 16 + li] = sacc[mt][nt][r];
    __syncthreads();

    // ---- phase 2: cross-wave reduce + online softmax (16 threads/row) ----
    {
      const int row = tid >> 4;
      const int c0 = (tid & 15) * 2;
      float s0 = 0.f, s1 = 0.f;
      #pragma unroll
      for (int i = 0; i < 8; ++i) {
        float2 v = *(const float2*)&buf[i][row][c0];
        s0 += v.x; s1 += v.y;
      }
      if constexpr (PATH == 1) {
        if (n0 + c0 >= LL)     s0 = -1e30f;
        if (n0 + c0 + 1 >= LL) s1 = -1e30f;
      }
      float mx = fmaxf(s0, s1);
      mx = fmaxf(mx, __shfl_xor(mx, 1));
      mx = fmaxf(mx, __shfl_xor(mx, 2));
      mx = fmaxf(mx, __shfl_xor(mx, 4));
      mx = fmaxf(mx, __shfl_xor(mx, 8));
      const float m_old = m_l[row];
      const float l_old = l_l[row];
      const float m_new = fmaxf(m_old, mx);
      const float sc = exp2f((m_old - m_new) * LOG2E);
      const float p0 = exp2f((s0 - m_new) * LOG2E);
      const float p1 = exp2f((s1 - m_new) * LOG2E);
      float ts = p0 + p1;
      ts += __shfl_xor(ts, 1);
      ts += __shfl_xor(ts, 2);
      ts += __shfl_xor(ts, 4);
      ts += __shfl_xor(ts, 8);
      if ((tid & 15) == 0) {           // sub-lane 0 of the row (same wave: in-order vs reads)
        m_l[row] = m_new;
        l_l[row] = l_old * sc + ts;
        sc_l[row] = sc;
      }
      *(unsigned*)&Pl[row][c0] = packrn(p0, p1);
    }
    __syncthreads();

    // ---- phase 3: rescale O, PV into this wave's D-slice ----
    float scr[2][4];
    #pragma unroll
    for (int mt = 0; mt < 2; ++mt)
      #pragma unroll
      for (int r = 0; r < 4; ++r)
        scr[mt][r] = sc_l[mt * 16 + g * 4 + r];
    #pragma unroll
    for (int mt = 0; mt < 2; ++mt)
      #pragma unroll
      for (int dt = 0; dt < 8; ++dt)
        #pragma unroll
        for (int r = 0; r < 4; ++r)
          o[mt][dt][r] *= scr[mt][r];

    short8v pa0 = *(const short8v*)&Pl[li][g * 8];        // A frag: row=li, k=g*8+j
    short8v pa1 = *(const short8v*)&Pl[16 + li][g * 8];
    #pragma unroll
    for (int dt = 0; dt < 8; ++dt) {
      short8v vb;
      if constexpr (PATH == 0) {
        size_t off = ((size_t)(b * HH) + dbase + dt * 16 + li) * LPAD + n0 + g * 8;
        vb = *(const short8v*)(v_t + off);                // B frag: col=li(d), k=n contiguous
      } else {
        frag_cast fc;
        const int d = dbase + dt * 16 + li;
        #pragma unroll
        for (int jj = 0; jj < 4; ++jj) {
          int na = n0 + g * 8 + jj * 2;
          int nb2 = na + 1;
          int nca = (na < LL) ? na : 0;    // clamped rows have P==0
          int ncb = (nb2 < LL) ? nb2 : 0;
          const float* pva = (nca < PP) ? (prefix_v + (size_t)nca * HH + d)
                                        : (value + ((size_t)b * SS + (nca - PP)) * HH + d);
          const float* pvb = (ncb < PP) ? (prefix_v + (size_t)ncb * HH + d)
                                        : (value + ((size_t)b * SS + (ncb - PP)) * HH + d);
          fc.u[jj] = packrn(*pva, *pvb);
        }
        vb = fc.s;
      }
      o[0][dt] = __builtin_amdgcn_mfma_f32_16x16x32_bf16(pa0, vb, o[0][dt], 0, 0, 0);
      o[1][dt] = __builtin_amdgcn_mfma_f32_16x16x32_bf16(pa1, vb, o[1][dt], 0, 0, 0);
    }
    // no barrier needed: next phase 1 only rewrites buf (all reads done pre-barrier2)
  }

  // ---- finalize: normalize by l, write fp32 output ----
  float il[2][4];
  #pragma unroll
  for (int mt = 0; mt < 2; ++mt)
    #pragma unroll
    for (int r = 0; r < 4; ++r)
      il[mt][r] = 1.0f / l_l[mt * 16 + g * 4 + r];
  #pragma unroll
  for (int mt = 0; mt < 2; ++mt)
    #pragma unroll
    for (int dt = 0; dt < 8; ++dt)
      #pragma unroll
      for (int r = 0; r < 4; ++r)
        out[((size_t)(b * SS + q0 + mt * 16 + g * 4 + r)) * HH + dbase + dt * 16 + li]
            = o[mt][dt][r] * il[mt][r];
}

extern "C" void kernel_launch(void* const* d_in, const int* in_sizes, int n_in,
                              void* d_out, int out_size, void* d_ws, size_t ws_size,
                              hipStream_t stream) {
  const float* q        = (const float*)d_in[0];
  const float* key      = (const float*)d_in[1];
  const float* value    = (const float*)d_in[2];
  const float* prefix_k = (const float*)d_in[3];
  const float* prefix_v = (const float*)d_in[4];
  float* out = (float*)d_out;

  const size_t PLANE = (size_t)BB * LPAD * HH;        // elems (ushort) per plane
  const size_t NEED  = 3 * PLANE * sizeof(unsigned short);  // 101,449,728 B

  if (ws_size >= NEED) {
    unsigned short* k_hi = (unsigned short*)d_ws;
    unsigned short* k_lo = k_hi + PLANE;
    unsigned short* v_t  = k_lo + PLANE;
    conv_k<<<(BB * LPAD * 128) / 256, 256, 0, stream>>>(prefix_k, key, k_hi, k_lo);
    conv_v<<<dim3(NTILES, 16, BB), 256, 0, stream>>>(prefix_v, value, v_t);
    attn_fused<0><<<512, 512, 0, stream>>>(q, key, value, prefix_k, prefix_v,
                                           k_hi, k_lo, v_t, out);
  } else {
    attn_fused<1><<<512, 512, 0, stream>>>(q, key, value, prefix_k, prefix_v,
                                           nullptr, nullptr, nullptr, out);
  }
}